// Round 5
// baseline (190.714 us; speedup 1.0000x reference)
//
#include <hip/hip_runtime.h>
#include <hip/hip_bf16.h>

// S4 layer: y = irfft( rfft(pad(u)) * (rfft(pad(K)) + D) )[:L]
// B=16, H=128, L=4096, N=64. All fp32.
// k_conv2: DUAL-ROW radix-16 FFT4096 (packed-real: each 4096-complex row
// IS 8192 reals, hence the alpha/beta mirror pointwise).
// History: R2 interleaved-float4 64KB (41.6us) / R3 packed v_pk math
// (146.4 total) / R4 fft16z + split twiddle chains (flat -> conv2 is
// latency/barrier-bound at 2 blocks/CU, NOT VALU-bound).
// R5 (this round, occupancy pass): 32 KB LDS per block. One 4096-float2
// buffer; the two rows' exchanges run SEQUENTIALLY through it (A then B).
// Barriers 10->20, DS back to b64 (XOR patterns measured 0 conflicts in
// R0/R1), abt loaded twice (2nd pass L2-hot). In exchange: 4 blocks/CU
// (launch_bounds(256,4); natural VGPR 116 <= 128 so no forced spill),
// 16 waves/CU, 1024 blocks = exactly one residency round. Barrier waits
// now overlap with 3 other blocks instead of 1.
// Guardrails: WRITE_SIZE must stay 32768 KB (spill signal);
// SQ_LDS_BANK_CONFLICT ~0; if flat/regressed -> revert to R4 conv2.
// ws: [0,4MiB) atR 128x4096 float2 ; [4MiB,12MiB) abt 128x4096 float4
//   (abt scrambled in radix-16 order: slot tid+256c <-> k=kb+256c).

#define PI_F 3.14159265358979323846f

typedef float v2 __attribute__((ext_vector_type(2)));

__device__ __forceinline__ v2 tov2(float2 a) { return (v2){a.x, a.y}; }
__device__ __forceinline__ float2 tof2(v2 a) { return make_float2(a.x, a.y); }

// packed complex mul: 2x v_pk (mul + fma), swizzles fold to op_sel/neg
__device__ __forceinline__ v2 cmul(v2 a, v2 b) {
  v2 t = __builtin_shufflevector(a, a, 0, 0) * b;          // (ax bx, ax by)
  v2 bs = __builtin_shufflevector(b, b, 1, 0);             // (by, bx)
  v2 m = (v2){-bs.x, bs.y};                                // (-by, bx)
  return __builtin_shufflevector(a, a, 1, 1) * m + t;
}
// packed complex mul by constant (wr, wi)
__device__ __forceinline__ v2 cmulc(v2 a, float wr, float wi) {
  v2 t = __builtin_shufflevector(a, a, 0, 0) * (v2){wr, wi};
  return __builtin_shufflevector(a, a, 1, 1) * (v2){-wi, wr} + t;
}
// a * conj(b), packed
__device__ __forceinline__ v2 cmulcj(v2 a, v2 b) {
  v2 bc = (v2){b.x, -b.y};
  return cmul(a, bc);
}

__device__ __forceinline__ int ad(int k) { return k + (k >> 4); }   // pad-17
__device__ __forceinline__ int sw16(int j) { return j ^ ((j >> 4) & 15); }

template <int SIGN>
__device__ __forceinline__ void bfly4(v2& a, v2& b, v2& c, v2& d) {
  v2 t0 = a + c, t1 = a - c, t2 = b + d, t3 = b - d;
  a = t0 + t2;
  c = t0 - t2;
  v2 t3i = (v2){t3.y, -t3.x};  // -i * t3 (sign handled below)
  if (SIGN < 0) {
    b = t1 + t3i;
    d = t1 - t3i;
  } else {
    b = t1 - t3i;
    d = t1 + t3i;
  }
}

// shared tail of the 16-point DFT: constant twiddle layer + 2nd bfly layer
template <int SIGN>
__device__ __forceinline__ void fft16_tail(v2 v[16]) {
  const float sg = (float)SIGN;
  const float C1 = 0.92387953251128674f;
  const float S1 = 0.38268343236508978f;
  const float R2 = 0.70710678118654752f;
  v[5] = cmulc(v[5], C1, sg * S1);
  v[6] = cmulc(v[6], R2, sg * R2);
  v[7] = cmulc(v[7], S1, sg * C1);
  v[9] = cmulc(v[9], R2, sg * R2);
  v[10] = (SIGN < 0) ? (v2){v[10].y, -v[10].x} : (v2){-v[10].y, v[10].x};
  v[11] = cmulc(v[11], -R2, sg * R2);
  v[13] = cmulc(v[13], S1, sg * C1);
  v[14] = cmulc(v[14], -R2, sg * R2);
  v[15] = cmulc(v[15], -C1, -sg * S1);
  v2 w[16];
#pragma unroll
  for (int g = 0; g < 4; ++g) {
    v2 x0 = v[4 * g], x1 = v[4 * g + 1], x2 = v[4 * g + 2], x3 = v[4 * g + 3];
    bfly4<SIGN>(x0, x1, x2, x3);
    w[g] = x0; w[g + 4] = x1; w[g + 8] = x2; w[g + 12] = x3;
  }
#pragma unroll
  for (int i = 0; i < 16; ++i) v[i] = w[i];
}

// full 16-point DFT, natural in / natural out
template <int SIGN>
__device__ __forceinline__ void fft16(v2 v[16]) {
  bfly4<SIGN>(v[0], v[4], v[8], v[12]);
  bfly4<SIGN>(v[1], v[5], v[9], v[13]);
  bfly4<SIGN>(v[2], v[6], v[10], v[14]);
  bfly4<SIGN>(v[3], v[7], v[11], v[15]);
  fft16_tail<SIGN>(v);
}

// 16-point DFT with v[8..15] == 0 on entry (zero-padded half): stage-1
// bfly4 with c=d=0 collapses to 4 packed ops (a+b, a-b, a+-ib).
template <int SIGN>
__device__ __forceinline__ void fft16z(v2 v[16]) {
#pragma unroll
  for (int g = 0; g < 4; ++g) {
    v2 A = v[g], Bv = v[4 + g];
    v2 iB = (v2){Bv.y, -Bv.x};  // -i*B
    v[g] = A + Bv;
    v[8 + g] = A - Bv;
    if (SIGN < 0) {
      v[4 + g] = A + iB;
      v[12 + g] = A - iB;
    } else {
      v[4 + g] = A - iB;
      v[12 + g] = A + iB;
    }
  }
  fft16_tail<SIGN>(v);
}

// twiddles via two parallel running chains: cw walks w^1..w^7, cw2 walks
// w^8..w^15 from a sincos(8*ang) anchor. Depth 14 -> 7, +1 live v2 only.
__device__ __forceinline__ void tw_apply(v2 v[16], float ang) {
  float sn, cn, sn8, cn8;
  __sincosf(ang, &sn, &cn);
  __sincosf(8.0f * ang, &sn8, &cn8);
  v2 w1 = (v2){cn, sn}, cw = w1;
  v2 cw2 = (v2){cn8, sn8};
  v[8] = cmul(v[8], cw2);
#pragma unroll
  for (int g = 1; g < 8; ++g) {
    v[g] = cmul(v[g], cw);
    cw2 = cmul(cw2, w1);
    v[g + 8] = cmul(v[g + 8], cw2);
    if (g < 7) cw = cmul(cw, w1);
  }
}

__device__ __forceinline__ void tw_apply2(v2 va[16], v2 vb[16], float ang) {
  float sn, cn, sn8, cn8;
  __sincosf(ang, &sn, &cn);
  __sincosf(8.0f * ang, &sn8, &cn8);
  v2 w1 = (v2){cn, sn}, cw = w1;
  v2 cw2 = (v2){cn8, sn8};
  va[8] = cmul(va[8], cw2);
  vb[8] = cmul(vb[8], cw2);
#pragma unroll
  for (int g = 1; g < 8; ++g) {
    va[g] = cmul(va[g], cw);
    vb[g] = cmul(vb[g], cw);
    cw2 = cmul(cw2, w1);
    va[g + 8] = cmul(va[g + 8], cw2);
    vb[g + 8] = cmul(vb[g + 8], cw2);
    if (g < 7) cw = cmul(cw, w1);
  }
}

// ======== pad-17 single-row machinery (k_khat only; proven) ========
// ZHI: input has v[8..15] == 0 (second khat FFT) -> cheap first stage.
template <int SIGN, bool ZHI>
__device__ void fft4096_regs(v2 v[16], float2* lds, int tid) {
  const int a = tid & 15, g2 = tid >> 4;
  if (ZHI) fft16z<SIGN>(v); else fft16<SIGN>(v);
  tw_apply(v, (float)SIGN * (2.0f * PI_F / 4096.0f) * (float)tid);
  __syncthreads();
#pragma unroll
  for (int g = 0; g < 16; ++g) lds[tid * 17 + g] = tof2(v[g]);
  __syncthreads();
#pragma unroll
  for (int b = 0; b < 16; ++b) v[b] = tov2(lds[a * 17 + b * 272 + g2]);
  fft16<SIGN>(v);
  tw_apply(v, (float)SIGN * (2.0f * PI_F / 256.0f) * (float)a);
  __syncthreads();
#pragma unroll
  for (int b = 0; b < 16; ++b) lds[g2 * 17 + b * 273 + a] = tof2(v[b]);
  __syncthreads();
#pragma unroll
  for (int a2 = 0; a2 < 16; ++a2) v[a2] = tov2(lds[g2 * 17 + a * 273 + a2]);
  fft16<SIGN>(v);
  // no trailing barrier; callers must __syncthreads before reusing lds.
}

// ======== dual-row forward in 32 KB: rows exchange SEQUENTIALLY ========
// natural -> scrambled. One 4096-float2 buffer; row A exchanges, then B.
template <int SIGN>
__device__ void fft4096_x2_32k(v2 va[16], v2 vb[16], float2* Z, int tid) {
  const int a = tid & 15, g2 = tid >> 4;
  fft16z<SIGN>(va);
  fft16z<SIGN>(vb);
  tw_apply2(va, vb, (float)SIGN * (2.0f * PI_F / 4096.0f) * (float)tid);
  // exchange 1: row A then row B through the same 32 KB buffer
  __syncthreads();
#pragma unroll
  for (int g = 0; g < 16; ++g) Z[(tid << 4) | (g ^ a)] = tof2(va[g]);
  __syncthreads();
#pragma unroll
  for (int b = 0; b < 16; ++b)
    va[b] = tov2(Z[((a + 16 * b) << 4) | (g2 ^ a)]);
  __syncthreads();
#pragma unroll
  for (int g = 0; g < 16; ++g) Z[(tid << 4) | (g ^ a)] = tof2(vb[g]);
  __syncthreads();
#pragma unroll
  for (int b = 0; b < 16; ++b)
    vb[b] = tov2(Z[((a + 16 * b) << 4) | (g2 ^ a)]);
  fft16<SIGN>(va);
  fft16<SIGN>(vb);
  tw_apply2(va, vb, (float)SIGN * (2.0f * PI_F / 256.0f) * (float)a);
  // exchange 2
  __syncthreads();
#pragma unroll
  for (int b = 0; b < 16; ++b)
    Z[(g2 << 8) | (b << 4) | (a ^ b)] = tof2(va[b]);
  __syncthreads();
#pragma unroll
  for (int a2 = 0; a2 < 16; ++a2)
    va[a2] = tov2(Z[(g2 << 8) | (a << 4) | (a2 ^ a)]);
  __syncthreads();
#pragma unroll
  for (int b = 0; b < 16; ++b)
    Z[(g2 << 8) | (b << 4) | (a ^ b)] = tof2(vb[b]);
  __syncthreads();
#pragma unroll
  for (int a2 = 0; a2 < 16; ++a2)
    vb[a2] = tov2(Z[(g2 << 8) | (a << 4) | (a2 ^ a)]);
  fft16<SIGN>(va);
  fft16<SIGN>(vb);
  // no trailing barrier.
}

// ======== dual-row inverse in 32 KB: scrambled -> natural ========
template <int SIGN>
__device__ void fft4096_x2_s2n_32k(v2 va[16], v2 vb[16], float2* Z, int tid) {
  const int a = tid & 15, g2 = tid >> 4;
  fft16<SIGN>(va);
  fft16<SIGN>(vb);
  __syncthreads();  // guard callers' prior lds reads
#pragma unroll
  for (int r = 0; r < 16; ++r)
    Z[(g2 << 8) | (a << 4) | (r ^ a)] = tof2(va[r]);
  __syncthreads();
#pragma unroll
  for (int b = 0; b < 16; ++b)
    va[b] = tov2(Z[(g2 << 8) | (b << 4) | (a ^ b)]);
  __syncthreads();
#pragma unroll
  for (int r = 0; r < 16; ++r)
    Z[(g2 << 8) | (a << 4) | (r ^ a)] = tof2(vb[r]);
  __syncthreads();
#pragma unroll
  for (int b = 0; b < 16; ++b)
    vb[b] = tov2(Z[(g2 << 8) | (b << 4) | (a ^ b)]);
  tw_apply2(va, vb, (float)SIGN * (2.0f * PI_F / 256.0f) * (float)a);
  fft16<SIGN>(va);
  fft16<SIGN>(vb);
  __syncthreads();
#pragma unroll
  for (int r = 0; r < 16; ++r)
    Z[((16 * r + a) << 4) | (g2 ^ a)] = tof2(va[r]);
  __syncthreads();
#pragma unroll
  for (int g = 0; g < 16; ++g) va[g] = tov2(Z[(tid << 4) | (g ^ a)]);
  __syncthreads();
#pragma unroll
  for (int r = 0; r < 16; ++r)
    Z[((16 * r + a) << 4) | (g2 ^ a)] = tof2(vb[r]);
  __syncthreads();
#pragma unroll
  for (int g = 0; g < 16; ++g) vb[g] = tov2(Z[(tid << 4) | (g ^ a)]);
  tw_apply2(va, vb, (float)SIGN * (2.0f * PI_F / 4096.0f) * (float)tid);
  fft16<SIGN>(va);
  fft16<SIGN>(vb);
}

// ---------------- Kernel 1a: Cauchy sums -> atRoots (packed) ---------
__global__ __launch_bounds__(256) void k_cauchy(
    const float* __restrict__ Lre, const float* __restrict__ Lim,
    const float* __restrict__ Pri, const float* __restrict__ Bri,
    const float* __restrict__ Cri, const float* __restrict__ lstep,
    float2* __restrict__ atR) {
  __shared__ float4 pA[64];
  __shared__ float4 pB[64];
  __shared__ float2 pL[64];
  const int h = blockIdx.x >> 4;
  const int sub = blockIdx.x & 15;
  const int tid = threadIdx.x;
  if (tid < 64) {
    int base = h * 64 + tid;
    float lr = fminf(Lre[base], -1e-4f);
    float li = Lim[base];
    float pr = Pri[2 * base], pi = Pri[2 * base + 1];
    float br = Bri[2 * base], bi = Bri[2 * base + 1];
    float cr = Cri[2 * base], ci = Cri[2 * base + 1];
    pA[tid] = make_float4(cr * br + ci * bi, cr * bi - ci * br,
                          cr * pr + ci * pi, cr * pi - ci * pr);
    pB[tid] = make_float4(pr * br + pi * bi, pr * bi - pi * br,
                          pr * pr + pi * pi, 0.f);
    pL[tid] = make_float2(lr, li);
  }
  __syncthreads();
  const float istep = expf(-lstep[h]);
  const int m = sub * 256 + tid;
  float sn, cn;
  __sincosf(-(2.0f * PI_F / 4096.0f) * (float)m, &sn, &cn);
  const v2 T = (v2){0.5f * (1.0f + cn), 0.5f * sn};   // (trm, tim)
  const v2 Q = (v2){(1.0f - cn) * istep, -sn * istep};  // (qrm, qim)
  v2 S01 = (v2){0.f, 0.f}, S23 = (v2){0.f, 0.f}, S45 = (v2){0.f, 0.f},
     S67 = (v2){0.f, 0.f};
#pragma unroll 8
  for (int n = 0; n < 64; ++n) {
    float4 a = pA[n];
    float4 b = pB[n];
    v2 L = tov2(pL[n]);
    v2 d = Q - cmul(T, L);
    float inv = __builtin_amdgcn_rcpf(d.x * d.x + d.y * d.y);
    v2 s = d * (v2){inv, -inv};  // (sr, si)
    S01 += cmul((v2){a.x, a.y}, s);
    S23 += cmul((v2){a.z, a.w}, s);
    S45 += cmul((v2){b.x, b.y}, s);
    S67 += (v2){b.z, b.z} * s;
  }
  // epilogue (scalar, once)
  float trm = T.x, tim = T.y;
  float tS11r = trm * S67.x - tim * S67.y;
  float tS11i = trm * S67.y + tim * S67.x;
  float denr = 1.0f + tS11r, deni = tS11i;
  float dinv = 1.0f / (denr * denr + deni * deni);
  float P1r = S23.x * S45.x - S23.y * S45.y;
  float P1i = S23.x * S45.y + S23.y * S45.x;
  float P2r = trm * P1r - tim * P1i;
  float P2i = trm * P1i + tim * P1r;
  float Qr = (P2r * denr + P2i * deni) * dinv;
  float Qi = (P2i * denr - P2r * deni) * dinv;
  atR[h * 4096 + m] = make_float2(S01.x - Qr, S01.y - Qi);
}

// ------- Kernel 1b: atRoots -> alpha/beta table (radix-16 scramble) -----
__global__ __launch_bounds__(256, 4) void k_khat(
    const float2* __restrict__ atR, const float* __restrict__ Dp,
    float4* __restrict__ abt) {
  __shared__ float2 lds[4368];
  const int h = blockIdx.x;
  const int tid = threadIdx.x;
  v2 v[16];
#pragma unroll
  for (int c = 0; c < 16; ++c) v[c] = tov2(atR[h * 4096 + tid + 256 * c]);
  fft4096_regs<1, false>(v, lds, tid);  // unnorm inverse -> zK (scrambled)
  const int kb = (tid >> 4) + 16 * (tid & 15);
  float* ldsf = (float*)lds;
  const float s = 1.0f / 4096.0f;
  __syncthreads();
#pragma unroll
  for (int al = 0; al < 16; ++al) ldsf[ad(kb + 256 * al)] = v[al].x * s;
  __syncthreads();
#pragma unroll
  for (int c = 0; c < 8; ++c) {
    int n = tid + 256 * c;
    v[c] = (v2){ldsf[ad(2 * n)], ldsf[ad(2 * n + 1)]};
  }
#pragma unroll
  for (int c = 8; c < 16; ++c) v[c] = (v2){0.f, 0.f};
  fft4096_regs<-1, true>(v, lds, tid);  // forward; scrambled; zero half
  __syncthreads();
#pragma unroll
  for (int al = 0; al < 16; ++al) lds[ad(kb + 256 * al)] = tof2(v[al]);
  __syncthreads();
  const float Dh = Dp[h];
#pragma unroll
  for (int c = 0; c < 16; ++c) {
    int k = kb + 256 * c;
    float2 Zk = lds[ad(k)];
    float2 Zm = lds[ad((4096 - k) & 4095)];
    float Er = 0.5f * (Zk.x + Zm.x), Ei = 0.5f * (Zk.y - Zm.y);
    float Or = 0.5f * (Zk.y + Zm.y), Oi = 0.5f * (Zm.x - Zk.x);
    float s_, c_;
    __sincosf(-(PI_F / 4096.0f) * (float)k, &s_, &c_);
    float Gr = c_ * Or - s_ * Oi, Gi = c_ * Oi + s_ * Or;  // G = W*O
    float ar = (Er + Dh + s_ * Gr) * s;
    float ai = (Ei + s_ * Gi) * s;
    float br = (-c_ * Gi) * s;
    float bi = (c_ * Gr) * s;
    abt[h * 4096 + tid + 256 * c] = make_float4(ar, ai, br, bi);  // scrambled
  }
}

// ---------------- Kernel 2: dual-row FFT convolution, 32 KB ----------
// 1024 blocks: block i does rows i and i+1024 (same h, batches b and b+8).
// 32 KB LDS + VGPR<=128 -> 4 blocks/CU: exactly one residency round.
__global__ __launch_bounds__(256, 4) void k_conv2(
    const float* __restrict__ u, const float4* __restrict__ abt,
    float* __restrict__ y) {
  __shared__ float2 Z[4096];  // 32 KB single buffer; rows take turns
  const int i = blockIdx.x;  // 0..1023
  const int h = i & 127;
  const int tid = threadIdx.x;
  const float2* uA = (const float2*)(u + (size_t)i * 4096);
  const float2* uB = (const float2*)(u + (size_t)(i + 1024) * 4096);
  v2 va[16], vb[16];
#pragma unroll
  for (int c = 0; c < 8; ++c) {
    va[c] = tov2(uA[tid + 256 * c]);
    vb[c] = tov2(uB[tid + 256 * c]);
  }
#pragma unroll
  for (int c = 8; c < 16; ++c) {
    va[c] = (v2){0.f, 0.f};
    vb[c] = (v2){0.f, 0.f};
  }
  fft4096_x2_32k<-1>(va, vb, Z, tid);  // forward; v[al]=Z[kb+256al]
  const int kb = (tid >> 4) + 16 * (tid & 15);
  const float4* __restrict__ abrow = abt + h * 4096;
  // mirror + pointwise: row A, then row B (abt row read twice; L2-hot)
  __syncthreads();  // lagging exchange-2 reads done before overwrite
#pragma unroll
  for (int al = 0; al < 16; ++al) Z[sw16(kb + 256 * al)] = tof2(va[al]);
  __syncthreads();
#pragma unroll
  for (int al = 0; al < 16; ++al) {
    int k = kb + 256 * al;
    float2 zm = Z[sw16((4096 - k) & 4095)];
    float4 ab = abrow[tid + 256 * al];
    va[al] = cmul((v2){ab.x, ab.y}, va[al]) +
             cmulcj((v2){ab.z, ab.w}, tov2(zm));
  }
  __syncthreads();
#pragma unroll
  for (int al = 0; al < 16; ++al) Z[sw16(kb + 256 * al)] = tof2(vb[al]);
  __syncthreads();
#pragma unroll
  for (int al = 0; al < 16; ++al) {
    int k = kb + 256 * al;
    float2 zm = Z[sw16((4096 - k) & 4095)];
    float4 ab = abrow[tid + 256 * al];
    vb[al] = cmul((v2){ab.x, ab.y}, vb[al]) +
             cmulcj((v2){ab.z, ab.w}, tov2(zm));
  }
  fft4096_x2_s2n_32k<1>(va, vb, Z, tid);  // inverse (scale folded in ab)
  float2* yA = (float2*)(y + (size_t)i * 4096);
  float2* yB = (float2*)(y + (size_t)(i + 1024) * 4096);
#pragma unroll
  for (int c = 0; c < 8; ++c) {
    yA[tid + 256 * c] = tof2(va[c]);
    yB[tid + 256 * c] = tof2(vb[c]);
  }
}

extern "C" void kernel_launch(void* const* d_in, const int* in_sizes, int n_in,
                              void* d_out, int out_size, void* d_ws,
                              size_t ws_size, hipStream_t stream) {
  (void)in_sizes; (void)n_in; (void)out_size; (void)ws_size;
  const float* u = (const float*)d_in[0];
  const float* Lre = (const float*)d_in[1];
  const float* Lim = (const float*)d_in[2];
  const float* Pri = (const float*)d_in[3];
  const float* Bri = (const float*)d_in[4];
  const float* Cri = (const float*)d_in[5];
  const float* lst = (const float*)d_in[6];
  const float* Dp = (const float*)d_in[7];
  float* y = (float*)d_out;
  float2* atR = (float2*)d_ws;                                     // 4 MiB
  float4* abt = (float4*)((char*)d_ws + (size_t)4 * 1024 * 1024);  // 8 MiB

  k_cauchy<<<2048, 256, 0, stream>>>(Lre, Lim, Pri, Bri, Cri, lst, atR);
  k_khat<<<128, 256, 0, stream>>>(atR, Dp, abt);
  k_conv2<<<1024, 256, 0, stream>>>(u, abt, y);
}

// Round 6
// 165.787 us; speedup vs baseline: 1.1504x; 1.1504x over previous
//
#include <hip/hip_runtime.h>
#include <hip/hip_bf16.h>

// S4 layer: y = irfft( rfft(pad(u)) * (rfft(pad(K)) + D) )[:L]
// B=16, H=128, L=4096, N=64. All fp32.
// k_conv2: DUAL-ROW radix-16 FFT4096 (packed-real: each 4096-complex row
// IS 8192 reals, hence the alpha/beta mirror pointwise).
// History: R2 interleaved-float4 64KB (41.6us) / R3 packed v_pk math /
// R4 fft16z + split twiddle chains (flat -> conv2 latency/barrier-bound
// at 2 blocks/CU) / R5 32KB+launch_bounds(256,4): hipcc drove VGPR to 64
// -> v[16] spilled (WRITE_SIZE 182MB, 72-119us). NEVER pass a min-waves
// arg that implies a VGPR cap <= natural (116): hipcc lands at 64 and
// spills. R6 (this round): SAME 32KB structure, launch_bounds(256) ->
// natural ~116 VGPR <= 128 cap already gives 4 waves/SIMD; with 32KB LDS
// (5 blocks/CU) the occupancy limit is 4 blocks/CU = 16 waves/CU - the
// R5 goal without the spill. One-line change to isolate the variable.
// Guardrails: WRITE_SIZE 32768 KB exactly (spill signal), VGPR <= 128;
// if clean and conv2 >= 38us -> occupancy thesis dead, revert to R4.
// ws: [0,4MiB) atR 128x4096 float2 ; [4MiB,12MiB) abt 128x4096 float4
//   (abt scrambled in radix-16 order: slot tid+256c <-> k=kb+256c).

#define PI_F 3.14159265358979323846f

typedef float v2 __attribute__((ext_vector_type(2)));

__device__ __forceinline__ v2 tov2(float2 a) { return (v2){a.x, a.y}; }
__device__ __forceinline__ float2 tof2(v2 a) { return make_float2(a.x, a.y); }

// packed complex mul: 2x v_pk (mul + fma), swizzles fold to op_sel/neg
__device__ __forceinline__ v2 cmul(v2 a, v2 b) {
  v2 t = __builtin_shufflevector(a, a, 0, 0) * b;          // (ax bx, ax by)
  v2 bs = __builtin_shufflevector(b, b, 1, 0);             // (by, bx)
  v2 m = (v2){-bs.x, bs.y};                                // (-by, bx)
  return __builtin_shufflevector(a, a, 1, 1) * m + t;
}
// packed complex mul by constant (wr, wi)
__device__ __forceinline__ v2 cmulc(v2 a, float wr, float wi) {
  v2 t = __builtin_shufflevector(a, a, 0, 0) * (v2){wr, wi};
  return __builtin_shufflevector(a, a, 1, 1) * (v2){-wi, wr} + t;
}
// a * conj(b), packed
__device__ __forceinline__ v2 cmulcj(v2 a, v2 b) {
  v2 bc = (v2){b.x, -b.y};
  return cmul(a, bc);
}

__device__ __forceinline__ int ad(int k) { return k + (k >> 4); }   // pad-17
__device__ __forceinline__ int sw16(int j) { return j ^ ((j >> 4) & 15); }

template <int SIGN>
__device__ __forceinline__ void bfly4(v2& a, v2& b, v2& c, v2& d) {
  v2 t0 = a + c, t1 = a - c, t2 = b + d, t3 = b - d;
  a = t0 + t2;
  c = t0 - t2;
  v2 t3i = (v2){t3.y, -t3.x};  // -i * t3 (sign handled below)
  if (SIGN < 0) {
    b = t1 + t3i;
    d = t1 - t3i;
  } else {
    b = t1 - t3i;
    d = t1 + t3i;
  }
}

// shared tail of the 16-point DFT: constant twiddle layer + 2nd bfly layer
template <int SIGN>
__device__ __forceinline__ void fft16_tail(v2 v[16]) {
  const float sg = (float)SIGN;
  const float C1 = 0.92387953251128674f;
  const float S1 = 0.38268343236508978f;
  const float R2 = 0.70710678118654752f;
  v[5] = cmulc(v[5], C1, sg * S1);
  v[6] = cmulc(v[6], R2, sg * R2);
  v[7] = cmulc(v[7], S1, sg * C1);
  v[9] = cmulc(v[9], R2, sg * R2);
  v[10] = (SIGN < 0) ? (v2){v[10].y, -v[10].x} : (v2){-v[10].y, v[10].x};
  v[11] = cmulc(v[11], -R2, sg * R2);
  v[13] = cmulc(v[13], S1, sg * C1);
  v[14] = cmulc(v[14], -R2, sg * R2);
  v[15] = cmulc(v[15], -C1, -sg * S1);
  v2 w[16];
#pragma unroll
  for (int g = 0; g < 4; ++g) {
    v2 x0 = v[4 * g], x1 = v[4 * g + 1], x2 = v[4 * g + 2], x3 = v[4 * g + 3];
    bfly4<SIGN>(x0, x1, x2, x3);
    w[g] = x0; w[g + 4] = x1; w[g + 8] = x2; w[g + 12] = x3;
  }
#pragma unroll
  for (int i = 0; i < 16; ++i) v[i] = w[i];
}

// full 16-point DFT, natural in / natural out
template <int SIGN>
__device__ __forceinline__ void fft16(v2 v[16]) {
  bfly4<SIGN>(v[0], v[4], v[8], v[12]);
  bfly4<SIGN>(v[1], v[5], v[9], v[13]);
  bfly4<SIGN>(v[2], v[6], v[10], v[14]);
  bfly4<SIGN>(v[3], v[7], v[11], v[15]);
  fft16_tail<SIGN>(v);
}

// 16-point DFT with v[8..15] == 0 on entry (zero-padded half): stage-1
// bfly4 with c=d=0 collapses to 4 packed ops (a+b, a-b, a+-ib).
template <int SIGN>
__device__ __forceinline__ void fft16z(v2 v[16]) {
#pragma unroll
  for (int g = 0; g < 4; ++g) {
    v2 A = v[g], Bv = v[4 + g];
    v2 iB = (v2){Bv.y, -Bv.x};  // -i*B
    v[g] = A + Bv;
    v[8 + g] = A - Bv;
    if (SIGN < 0) {
      v[4 + g] = A + iB;
      v[12 + g] = A - iB;
    } else {
      v[4 + g] = A - iB;
      v[12 + g] = A + iB;
    }
  }
  fft16_tail<SIGN>(v);
}

// twiddles via two parallel running chains: cw walks w^1..w^7, cw2 walks
// w^8..w^15 from a sincos(8*ang) anchor. Depth 14 -> 7, +1 live v2 only.
__device__ __forceinline__ void tw_apply(v2 v[16], float ang) {
  float sn, cn, sn8, cn8;
  __sincosf(ang, &sn, &cn);
  __sincosf(8.0f * ang, &sn8, &cn8);
  v2 w1 = (v2){cn, sn}, cw = w1;
  v2 cw2 = (v2){cn8, sn8};
  v[8] = cmul(v[8], cw2);
#pragma unroll
  for (int g = 1; g < 8; ++g) {
    v[g] = cmul(v[g], cw);
    cw2 = cmul(cw2, w1);
    v[g + 8] = cmul(v[g + 8], cw2);
    if (g < 7) cw = cmul(cw, w1);
  }
}

__device__ __forceinline__ void tw_apply2(v2 va[16], v2 vb[16], float ang) {
  float sn, cn, sn8, cn8;
  __sincosf(ang, &sn, &cn);
  __sincosf(8.0f * ang, &sn8, &cn8);
  v2 w1 = (v2){cn, sn}, cw = w1;
  v2 cw2 = (v2){cn8, sn8};
  va[8] = cmul(va[8], cw2);
  vb[8] = cmul(vb[8], cw2);
#pragma unroll
  for (int g = 1; g < 8; ++g) {
    va[g] = cmul(va[g], cw);
    vb[g] = cmul(vb[g], cw);
    cw2 = cmul(cw2, w1);
    va[g + 8] = cmul(va[g + 8], cw2);
    vb[g + 8] = cmul(vb[g + 8], cw2);
    if (g < 7) cw = cmul(cw, w1);
  }
}

// ======== pad-17 single-row machinery (k_khat only; proven) ========
// ZHI: input has v[8..15] == 0 (second khat FFT) -> cheap first stage.
template <int SIGN, bool ZHI>
__device__ void fft4096_regs(v2 v[16], float2* lds, int tid) {
  const int a = tid & 15, g2 = tid >> 4;
  if (ZHI) fft16z<SIGN>(v); else fft16<SIGN>(v);
  tw_apply(v, (float)SIGN * (2.0f * PI_F / 4096.0f) * (float)tid);
  __syncthreads();
#pragma unroll
  for (int g = 0; g < 16; ++g) lds[tid * 17 + g] = tof2(v[g]);
  __syncthreads();
#pragma unroll
  for (int b = 0; b < 16; ++b) v[b] = tov2(lds[a * 17 + b * 272 + g2]);
  fft16<SIGN>(v);
  tw_apply(v, (float)SIGN * (2.0f * PI_F / 256.0f) * (float)a);
  __syncthreads();
#pragma unroll
  for (int b = 0; b < 16; ++b) lds[g2 * 17 + b * 273 + a] = tof2(v[b]);
  __syncthreads();
#pragma unroll
  for (int a2 = 0; a2 < 16; ++a2) v[a2] = tov2(lds[g2 * 17 + a * 273 + a2]);
  fft16<SIGN>(v);
  // no trailing barrier; callers must __syncthreads before reusing lds.
}

// ======== dual-row forward in 32 KB: rows exchange SEQUENTIALLY ========
// natural -> scrambled. One 4096-float2 buffer; row A exchanges, then B.
template <int SIGN>
__device__ void fft4096_x2_32k(v2 va[16], v2 vb[16], float2* Z, int tid) {
  const int a = tid & 15, g2 = tid >> 4;
  fft16z<SIGN>(va);
  fft16z<SIGN>(vb);
  tw_apply2(va, vb, (float)SIGN * (2.0f * PI_F / 4096.0f) * (float)tid);
  // exchange 1: row A then row B through the same 32 KB buffer
  __syncthreads();
#pragma unroll
  for (int g = 0; g < 16; ++g) Z[(tid << 4) | (g ^ a)] = tof2(va[g]);
  __syncthreads();
#pragma unroll
  for (int b = 0; b < 16; ++b)
    va[b] = tov2(Z[((a + 16 * b) << 4) | (g2 ^ a)]);
  __syncthreads();
#pragma unroll
  for (int g = 0; g < 16; ++g) Z[(tid << 4) | (g ^ a)] = tof2(vb[g]);
  __syncthreads();
#pragma unroll
  for (int b = 0; b < 16; ++b)
    vb[b] = tov2(Z[((a + 16 * b) << 4) | (g2 ^ a)]);
  fft16<SIGN>(va);
  fft16<SIGN>(vb);
  tw_apply2(va, vb, (float)SIGN * (2.0f * PI_F / 256.0f) * (float)a);
  // exchange 2
  __syncthreads();
#pragma unroll
  for (int b = 0; b < 16; ++b)
    Z[(g2 << 8) | (b << 4) | (a ^ b)] = tof2(va[b]);
  __syncthreads();
#pragma unroll
  for (int a2 = 0; a2 < 16; ++a2)
    va[a2] = tov2(Z[(g2 << 8) | (a << 4) | (a2 ^ a)]);
  __syncthreads();
#pragma unroll
  for (int b = 0; b < 16; ++b)
    Z[(g2 << 8) | (b << 4) | (a ^ b)] = tof2(vb[b]);
  __syncthreads();
#pragma unroll
  for (int a2 = 0; a2 < 16; ++a2)
    vb[a2] = tov2(Z[(g2 << 8) | (a << 4) | (a2 ^ a)]);
  fft16<SIGN>(va);
  fft16<SIGN>(vb);
  // no trailing barrier.
}

// ======== dual-row inverse in 32 KB: scrambled -> natural ========
template <int SIGN>
__device__ void fft4096_x2_s2n_32k(v2 va[16], v2 vb[16], float2* Z, int tid) {
  const int a = tid & 15, g2 = tid >> 4;
  fft16<SIGN>(va);
  fft16<SIGN>(vb);
  __syncthreads();  // guard callers' prior lds reads
#pragma unroll
  for (int r = 0; r < 16; ++r)
    Z[(g2 << 8) | (a << 4) | (r ^ a)] = tof2(va[r]);
  __syncthreads();
#pragma unroll
  for (int b = 0; b < 16; ++b)
    va[b] = tov2(Z[(g2 << 8) | (b << 4) | (a ^ b)]);
  __syncthreads();
#pragma unroll
  for (int r = 0; r < 16; ++r)
    Z[(g2 << 8) | (a << 4) | (r ^ a)] = tof2(vb[r]);
  __syncthreads();
#pragma unroll
  for (int b = 0; b < 16; ++b)
    vb[b] = tov2(Z[(g2 << 8) | (b << 4) | (a ^ b)]);
  tw_apply2(va, vb, (float)SIGN * (2.0f * PI_F / 256.0f) * (float)a);
  fft16<SIGN>(va);
  fft16<SIGN>(vb);
  __syncthreads();
#pragma unroll
  for (int r = 0; r < 16; ++r)
    Z[((16 * r + a) << 4) | (g2 ^ a)] = tof2(va[r]);
  __syncthreads();
#pragma unroll
  for (int g = 0; g < 16; ++g) va[g] = tov2(Z[(tid << 4) | (g ^ a)]);
  __syncthreads();
#pragma unroll
  for (int r = 0; r < 16; ++r)
    Z[((16 * r + a) << 4) | (g2 ^ a)] = tof2(vb[r]);
  __syncthreads();
#pragma unroll
  for (int g = 0; g < 16; ++g) vb[g] = tov2(Z[(tid << 4) | (g ^ a)]);
  tw_apply2(va, vb, (float)SIGN * (2.0f * PI_F / 4096.0f) * (float)tid);
  fft16<SIGN>(va);
  fft16<SIGN>(vb);
}

// ---------------- Kernel 1a: Cauchy sums -> atRoots (packed) ---------
__global__ __launch_bounds__(256) void k_cauchy(
    const float* __restrict__ Lre, const float* __restrict__ Lim,
    const float* __restrict__ Pri, const float* __restrict__ Bri,
    const float* __restrict__ Cri, const float* __restrict__ lstep,
    float2* __restrict__ atR) {
  __shared__ float4 pA[64];
  __shared__ float4 pB[64];
  __shared__ float2 pL[64];
  const int h = blockIdx.x >> 4;
  const int sub = blockIdx.x & 15;
  const int tid = threadIdx.x;
  if (tid < 64) {
    int base = h * 64 + tid;
    float lr = fminf(Lre[base], -1e-4f);
    float li = Lim[base];
    float pr = Pri[2 * base], pi = Pri[2 * base + 1];
    float br = Bri[2 * base], bi = Bri[2 * base + 1];
    float cr = Cri[2 * base], ci = Cri[2 * base + 1];
    pA[tid] = make_float4(cr * br + ci * bi, cr * bi - ci * br,
                          cr * pr + ci * pi, cr * pi - ci * pr);
    pB[tid] = make_float4(pr * br + pi * bi, pr * bi - pi * br,
                          pr * pr + pi * pi, 0.f);
    pL[tid] = make_float2(lr, li);
  }
  __syncthreads();
  const float istep = expf(-lstep[h]);
  const int m = sub * 256 + tid;
  float sn, cn;
  __sincosf(-(2.0f * PI_F / 4096.0f) * (float)m, &sn, &cn);
  const v2 T = (v2){0.5f * (1.0f + cn), 0.5f * sn};   // (trm, tim)
  const v2 Q = (v2){(1.0f - cn) * istep, -sn * istep};  // (qrm, qim)
  v2 S01 = (v2){0.f, 0.f}, S23 = (v2){0.f, 0.f}, S45 = (v2){0.f, 0.f},
     S67 = (v2){0.f, 0.f};
#pragma unroll 8
  for (int n = 0; n < 64; ++n) {
    float4 a = pA[n];
    float4 b = pB[n];
    v2 L = tov2(pL[n]);
    v2 d = Q - cmul(T, L);
    float inv = __builtin_amdgcn_rcpf(d.x * d.x + d.y * d.y);
    v2 s = d * (v2){inv, -inv};  // (sr, si)
    S01 += cmul((v2){a.x, a.y}, s);
    S23 += cmul((v2){a.z, a.w}, s);
    S45 += cmul((v2){b.x, b.y}, s);
    S67 += (v2){b.z, b.z} * s;
  }
  // epilogue (scalar, once)
  float trm = T.x, tim = T.y;
  float tS11r = trm * S67.x - tim * S67.y;
  float tS11i = trm * S67.y + tim * S67.x;
  float denr = 1.0f + tS11r, deni = tS11i;
  float dinv = 1.0f / (denr * denr + deni * deni);
  float P1r = S23.x * S45.x - S23.y * S45.y;
  float P1i = S23.x * S45.y + S23.y * S45.x;
  float P2r = trm * P1r - tim * P1i;
  float P2i = trm * P1i + tim * P1r;
  float Qr = (P2r * denr + P2i * deni) * dinv;
  float Qi = (P2i * denr - P2r * deni) * dinv;
  atR[h * 4096 + m] = make_float2(S01.x - Qr, S01.y - Qi);
}

// ------- Kernel 1b: atRoots -> alpha/beta table (radix-16 scramble) -----
__global__ __launch_bounds__(256, 4) void k_khat(
    const float2* __restrict__ atR, const float* __restrict__ Dp,
    float4* __restrict__ abt) {
  __shared__ float2 lds[4368];
  const int h = blockIdx.x;
  const int tid = threadIdx.x;
  v2 v[16];
#pragma unroll
  for (int c = 0; c < 16; ++c) v[c] = tov2(atR[h * 4096 + tid + 256 * c]);
  fft4096_regs<1, false>(v, lds, tid);  // unnorm inverse -> zK (scrambled)
  const int kb = (tid >> 4) + 16 * (tid & 15);
  float* ldsf = (float*)lds;
  const float s = 1.0f / 4096.0f;
  __syncthreads();
#pragma unroll
  for (int al = 0; al < 16; ++al) ldsf[ad(kb + 256 * al)] = v[al].x * s;
  __syncthreads();
#pragma unroll
  for (int c = 0; c < 8; ++c) {
    int n = tid + 256 * c;
    v[c] = (v2){ldsf[ad(2 * n)], ldsf[ad(2 * n + 1)]};
  }
#pragma unroll
  for (int c = 8; c < 16; ++c) v[c] = (v2){0.f, 0.f};
  fft4096_regs<-1, true>(v, lds, tid);  // forward; scrambled; zero half
  __syncthreads();
#pragma unroll
  for (int al = 0; al < 16; ++al) lds[ad(kb + 256 * al)] = tof2(v[al]);
  __syncthreads();
  const float Dh = Dp[h];
#pragma unroll
  for (int c = 0; c < 16; ++c) {
    int k = kb + 256 * c;
    float2 Zk = lds[ad(k)];
    float2 Zm = lds[ad((4096 - k) & 4095)];
    float Er = 0.5f * (Zk.x + Zm.x), Ei = 0.5f * (Zk.y - Zm.y);
    float Or = 0.5f * (Zk.y + Zm.y), Oi = 0.5f * (Zm.x - Zk.x);
    float s_, c_;
    __sincosf(-(PI_F / 4096.0f) * (float)k, &s_, &c_);
    float Gr = c_ * Or - s_ * Oi, Gi = c_ * Oi + s_ * Or;  // G = W*O
    float ar = (Er + Dh + s_ * Gr) * s;
    float ai = (Ei + s_ * Gi) * s;
    float br = (-c_ * Gi) * s;
    float bi = (c_ * Gr) * s;
    abt[h * 4096 + tid + 256 * c] = make_float4(ar, ai, br, bi);  // scrambled
  }
}

// ---------------- Kernel 2: dual-row FFT convolution, 32 KB ----------
// 1024 blocks: block i does rows i and i+1024 (same h, batches b and b+8).
// 32 KB LDS; natural VGPR (~116 <= 128) -> 4 blocks/CU without any
// forced cap (R5 lesson: forced min-waves arg made hipcc pick 64 VGPR
// and spill v[16] to scratch).
__global__ __launch_bounds__(256) void k_conv2(
    const float* __restrict__ u, const float4* __restrict__ abt,
    float* __restrict__ y) {
  __shared__ float2 Z[4096];  // 32 KB single buffer; rows take turns
  const int i = blockIdx.x;  // 0..1023
  const int h = i & 127;
  const int tid = threadIdx.x;
  const float2* uA = (const float2*)(u + (size_t)i * 4096);
  const float2* uB = (const float2*)(u + (size_t)(i + 1024) * 4096);
  v2 va[16], vb[16];
#pragma unroll
  for (int c = 0; c < 8; ++c) {
    va[c] = tov2(uA[tid + 256 * c]);
    vb[c] = tov2(uB[tid + 256 * c]);
  }
#pragma unroll
  for (int c = 8; c < 16; ++c) {
    va[c] = (v2){0.f, 0.f};
    vb[c] = (v2){0.f, 0.f};
  }
  fft4096_x2_32k<-1>(va, vb, Z, tid);  // forward; v[al]=Z[kb+256al]
  const int kb = (tid >> 4) + 16 * (tid & 15);
  const float4* __restrict__ abrow = abt + h * 4096;
  // mirror + pointwise: row A, then row B (abt row read twice; L2-hot)
  __syncthreads();  // lagging exchange-2 reads done before overwrite
#pragma unroll
  for (int al = 0; al < 16; ++al) Z[sw16(kb + 256 * al)] = tof2(va[al]);
  __syncthreads();
#pragma unroll
  for (int al = 0; al < 16; ++al) {
    int k = kb + 256 * al;
    float2 zm = Z[sw16((4096 - k) & 4095)];
    float4 ab = abrow[tid + 256 * al];
    va[al] = cmul((v2){ab.x, ab.y}, va[al]) +
             cmulcj((v2){ab.z, ab.w}, tov2(zm));
  }
  __syncthreads();
#pragma unroll
  for (int al = 0; al < 16; ++al) Z[sw16(kb + 256 * al)] = tof2(vb[al]);
  __syncthreads();
#pragma unroll
  for (int al = 0; al < 16; ++al) {
    int k = kb + 256 * al;
    float2 zm = Z[sw16((4096 - k) & 4095)];
    float4 ab = abrow[tid + 256 * al];
    vb[al] = cmul((v2){ab.x, ab.y}, vb[al]) +
             cmulcj((v2){ab.z, ab.w}, tov2(zm));
  }
  fft4096_x2_s2n_32k<1>(va, vb, Z, tid);  // inverse (scale folded in ab)
  float2* yA = (float2*)(y + (size_t)i * 4096);
  float2* yB = (float2*)(y + (size_t)(i + 1024) * 4096);
#pragma unroll
  for (int c = 0; c < 8; ++c) {
    yA[tid + 256 * c] = tof2(va[c]);
    yB[tid + 256 * c] = tof2(vb[c]);
  }
}

extern "C" void kernel_launch(void* const* d_in, const int* in_sizes, int n_in,
                              void* d_out, int out_size, void* d_ws,
                              size_t ws_size, hipStream_t stream) {
  (void)in_sizes; (void)n_in; (void)out_size; (void)ws_size;
  const float* u = (const float*)d_in[0];
  const float* Lre = (const float*)d_in[1];
  const float* Lim = (const float*)d_in[2];
  const float* Pri = (const float*)d_in[3];
  const float* Bri = (const float*)d_in[4];
  const float* Cri = (const float*)d_in[5];
  const float* lst = (const float*)d_in[6];
  const float* Dp = (const float*)d_in[7];
  float* y = (float*)d_out;
  float2* atR = (float2*)d_ws;                                     // 4 MiB
  float4* abt = (float4*)((char*)d_ws + (size_t)4 * 1024 * 1024);  // 8 MiB

  k_cauchy<<<2048, 256, 0, stream>>>(Lre, Lim, Pri, Bri, Cri, lst, atR);
  k_khat<<<128, 256, 0, stream>>>(atR, Dp, abt);
  k_conv2<<<1024, 256, 0, stream>>>(u, abt, y);
}

// Round 7
// 142.004 us; speedup vs baseline: 1.3430x; 1.1675x over previous
//
#include <hip/hip_runtime.h>
#include <hip/hip_bf16.h>

// S4 layer: y = irfft( rfft(pad(u)) * (rfft(pad(K)) + D) )[:L]
// B=16, H=128, L=4096, N=64. All fp32.
// k_conv2: DUAL-ROW radix-16 FFT4096, interleaved float4 64KB LDS (R2),
// packed v_pk math (R3), fft16z + split twiddle chains (R4). 146.4us.
// OCCUPANCY THESIS DEAD (R5/R6): 32KB sequential-exchange restructure
// raises natural VGPR to 136 (>128) and doubles barriers -> occupancy
// FELL (16->10%) and conv2 got worse (41.6->55us). Forced min-waves caps
// spill v[16] (R5: VGPR 64, WRITE_SIZE 182MB). conv2 stays at the R4
// structure: 64KB, launch_bounds(256,1), natural ~116 VGPR.
// R7 (this round): k_cauchy T-hoist. den = Q - T*L = T*(qt - L) with
// qt = Q/T once per thread; 1/T folds into the epilogue which SIMPLIFIES:
// atR = (1/T)[S01' - S23'S45'/(1+S67')]. Inner loop 3 ops -> 1.
// Guard rcp(max(|T|^2,1e-30)) for the T->0 bin (m=2048).
// ws: [0,4MiB) atR 128x4096 float2 ; [4MiB,12MiB) abt 128x4096 float4
//   (abt scrambled in radix-16 order: slot tid+256c <-> k=kb+256c).

#define PI_F 3.14159265358979323846f

typedef float v2 __attribute__((ext_vector_type(2)));

__device__ __forceinline__ v2 tov2(float2 a) { return (v2){a.x, a.y}; }
__device__ __forceinline__ float2 tof2(v2 a) { return make_float2(a.x, a.y); }

// packed complex mul: 2x v_pk (mul + fma), swizzles fold to op_sel/neg
__device__ __forceinline__ v2 cmul(v2 a, v2 b) {
  v2 t = __builtin_shufflevector(a, a, 0, 0) * b;          // (ax bx, ax by)
  v2 bs = __builtin_shufflevector(b, b, 1, 0);             // (by, bx)
  v2 m = (v2){-bs.x, bs.y};                                // (-by, bx)
  return __builtin_shufflevector(a, a, 1, 1) * m + t;
}
// packed complex mul by constant (wr, wi)
__device__ __forceinline__ v2 cmulc(v2 a, float wr, float wi) {
  v2 t = __builtin_shufflevector(a, a, 0, 0) * (v2){wr, wi};
  return __builtin_shufflevector(a, a, 1, 1) * (v2){-wi, wr} + t;
}
// a * conj(b), packed
__device__ __forceinline__ v2 cmulcj(v2 a, v2 b) {
  v2 bc = (v2){b.x, -b.y};
  return cmul(a, bc);
}

__device__ __forceinline__ int ad(int k) { return k + (k >> 4); }   // pad-17
__device__ __forceinline__ int sw16(int j) { return j ^ ((j >> 4) & 15); }

template <int SIGN>
__device__ __forceinline__ void bfly4(v2& a, v2& b, v2& c, v2& d) {
  v2 t0 = a + c, t1 = a - c, t2 = b + d, t3 = b - d;
  a = t0 + t2;
  c = t0 - t2;
  v2 t3i = (v2){t3.y, -t3.x};  // -i * t3 (sign handled below)
  if (SIGN < 0) {
    b = t1 + t3i;
    d = t1 - t3i;
  } else {
    b = t1 - t3i;
    d = t1 + t3i;
  }
}

// shared tail of the 16-point DFT: constant twiddle layer + 2nd bfly layer
template <int SIGN>
__device__ __forceinline__ void fft16_tail(v2 v[16]) {
  const float sg = (float)SIGN;
  const float C1 = 0.92387953251128674f;
  const float S1 = 0.38268343236508978f;
  const float R2 = 0.70710678118654752f;
  v[5] = cmulc(v[5], C1, sg * S1);
  v[6] = cmulc(v[6], R2, sg * R2);
  v[7] = cmulc(v[7], S1, sg * C1);
  v[9] = cmulc(v[9], R2, sg * R2);
  v[10] = (SIGN < 0) ? (v2){v[10].y, -v[10].x} : (v2){-v[10].y, v[10].x};
  v[11] = cmulc(v[11], -R2, sg * R2);
  v[13] = cmulc(v[13], S1, sg * C1);
  v[14] = cmulc(v[14], -R2, sg * R2);
  v[15] = cmulc(v[15], -C1, -sg * S1);
  v2 w[16];
#pragma unroll
  for (int g = 0; g < 4; ++g) {
    v2 x0 = v[4 * g], x1 = v[4 * g + 1], x2 = v[4 * g + 2], x3 = v[4 * g + 3];
    bfly4<SIGN>(x0, x1, x2, x3);
    w[g] = x0; w[g + 4] = x1; w[g + 8] = x2; w[g + 12] = x3;
  }
#pragma unroll
  for (int i = 0; i < 16; ++i) v[i] = w[i];
}

// full 16-point DFT, natural in / natural out
template <int SIGN>
__device__ __forceinline__ void fft16(v2 v[16]) {
  bfly4<SIGN>(v[0], v[4], v[8], v[12]);
  bfly4<SIGN>(v[1], v[5], v[9], v[13]);
  bfly4<SIGN>(v[2], v[6], v[10], v[14]);
  bfly4<SIGN>(v[3], v[7], v[11], v[15]);
  fft16_tail<SIGN>(v);
}

// 16-point DFT with v[8..15] == 0 on entry (zero-padded half): stage-1
// bfly4 with c=d=0 collapses to 4 packed ops (a+b, a-b, a+-ib).
template <int SIGN>
__device__ __forceinline__ void fft16z(v2 v[16]) {
#pragma unroll
  for (int g = 0; g < 4; ++g) {
    v2 A = v[g], Bv = v[4 + g];
    v2 iB = (v2){Bv.y, -Bv.x};  // -i*B
    v[g] = A + Bv;
    v[8 + g] = A - Bv;
    if (SIGN < 0) {
      v[4 + g] = A + iB;
      v[12 + g] = A - iB;
    } else {
      v[4 + g] = A - iB;
      v[12 + g] = A + iB;
    }
  }
  fft16_tail<SIGN>(v);
}

// twiddles via two parallel running chains: cw walks w^1..w^7, cw2 walks
// w^8..w^15 from a sincos(8*ang) anchor. Depth 14 -> 7, +1 live v2 only.
__device__ __forceinline__ void tw_apply(v2 v[16], float ang) {
  float sn, cn, sn8, cn8;
  __sincosf(ang, &sn, &cn);
  __sincosf(8.0f * ang, &sn8, &cn8);
  v2 w1 = (v2){cn, sn}, cw = w1;
  v2 cw2 = (v2){cn8, sn8};
  v[8] = cmul(v[8], cw2);
#pragma unroll
  for (int g = 1; g < 8; ++g) {
    v[g] = cmul(v[g], cw);
    cw2 = cmul(cw2, w1);
    v[g + 8] = cmul(v[g + 8], cw2);
    if (g < 7) cw = cmul(cw, w1);
  }
}

__device__ __forceinline__ void tw_apply2(v2 va[16], v2 vb[16], float ang) {
  float sn, cn, sn8, cn8;
  __sincosf(ang, &sn, &cn);
  __sincosf(8.0f * ang, &sn8, &cn8);
  v2 w1 = (v2){cn, sn}, cw = w1;
  v2 cw2 = (v2){cn8, sn8};
  va[8] = cmul(va[8], cw2);
  vb[8] = cmul(vb[8], cw2);
#pragma unroll
  for (int g = 1; g < 8; ++g) {
    va[g] = cmul(va[g], cw);
    vb[g] = cmul(vb[g], cw);
    cw2 = cmul(cw2, w1);
    va[g + 8] = cmul(va[g + 8], cw2);
    vb[g + 8] = cmul(vb[g + 8], cw2);
    if (g < 7) cw = cmul(cw, w1);
  }
}

// ======== pad-17 single-row machinery (k_khat only; proven) ========
// ZHI: input has v[8..15] == 0 (second khat FFT) -> cheap first stage.
template <int SIGN, bool ZHI>
__device__ void fft4096_regs(v2 v[16], float2* lds, int tid) {
  const int a = tid & 15, g2 = tid >> 4;
  if (ZHI) fft16z<SIGN>(v); else fft16<SIGN>(v);
  tw_apply(v, (float)SIGN * (2.0f * PI_F / 4096.0f) * (float)tid);
  __syncthreads();
#pragma unroll
  for (int g = 0; g < 16; ++g) lds[tid * 17 + g] = tof2(v[g]);
  __syncthreads();
#pragma unroll
  for (int b = 0; b < 16; ++b) v[b] = tov2(lds[a * 17 + b * 272 + g2]);
  fft16<SIGN>(v);
  tw_apply(v, (float)SIGN * (2.0f * PI_F / 256.0f) * (float)a);
  __syncthreads();
#pragma unroll
  for (int b = 0; b < 16; ++b) lds[g2 * 17 + b * 273 + a] = tof2(v[b]);
  __syncthreads();
#pragma unroll
  for (int a2 = 0; a2 < 16; ++a2) v[a2] = tov2(lds[g2 * 17 + a * 273 + a2]);
  fft16<SIGN>(v);
  // no trailing barrier; callers must __syncthreads before reusing lds.
}

// pack/unpack helpers for interleaved dual-row LDS (one b128 per pair)
__device__ __forceinline__ float4 pk(v2 a, v2 b) {
  return make_float4(a.x, a.y, b.x, b.y);
}

// ======== dual-row swizzled forward: natural -> scrambled ========
// Entry: va[8..15] = vb[8..15] = 0 (zero-padded conv input) -> fft16z.
// AB[s] holds {rowA, rowB} interleaved: one ds_write_b128/ds_read_b128
// moves both rows (half the DS ops of split A/B buffers).
template <int SIGN>
__device__ void fft4096_x2(v2 va[16], v2 vb[16], float4* AB, int tid) {
  const int a = tid & 15, g2 = tid >> 4;
  fft16z<SIGN>(va);
  fft16z<SIGN>(vb);
  tw_apply2(va, vb, (float)SIGN * (2.0f * PI_F / 4096.0f) * (float)tid);
  __syncthreads();
#pragma unroll
  for (int g = 0; g < 16; ++g) AB[(tid << 4) | (g ^ a)] = pk(va[g], vb[g]);
  __syncthreads();
#pragma unroll
  for (int b = 0; b < 16; ++b) {
    float4 t = AB[((a + 16 * b) << 4) | (g2 ^ a)];
    va[b] = (v2){t.x, t.y};
    vb[b] = (v2){t.z, t.w};
  }
  fft16<SIGN>(va);
  fft16<SIGN>(vb);
  tw_apply2(va, vb, (float)SIGN * (2.0f * PI_F / 256.0f) * (float)a);
  __syncthreads();
#pragma unroll
  for (int b = 0; b < 16; ++b)
    AB[(g2 << 8) | (b << 4) | (a ^ b)] = pk(va[b], vb[b]);
  __syncthreads();
#pragma unroll
  for (int a2 = 0; a2 < 16; ++a2) {
    float4 t = AB[(g2 << 8) | (a << 4) | (a2 ^ a)];
    va[a2] = (v2){t.x, t.y};
    vb[a2] = (v2){t.z, t.w};
  }
  fft16<SIGN>(va);
  fft16<SIGN>(vb);
  // no trailing barrier.
}

// ======== dual-row swizzled inverse: scrambled -> natural ========
template <int SIGN>
__device__ void fft4096_x2_s2n(v2 va[16], v2 vb[16], float4* AB, int tid) {
  const int a = tid & 15, g2 = tid >> 4;
  fft16<SIGN>(va);
  fft16<SIGN>(vb);
  __syncthreads();  // guard callers' prior lds reads
#pragma unroll
  for (int r = 0; r < 16; ++r)
    AB[(g2 << 8) | (a << 4) | (r ^ a)] = pk(va[r], vb[r]);
  __syncthreads();
#pragma unroll
  for (int b = 0; b < 16; ++b) {
    float4 t = AB[(g2 << 8) | (b << 4) | (a ^ b)];
    va[b] = (v2){t.x, t.y};
    vb[b] = (v2){t.z, t.w};
  }
  tw_apply2(va, vb, (float)SIGN * (2.0f * PI_F / 256.0f) * (float)a);
  fft16<SIGN>(va);
  fft16<SIGN>(vb);
  __syncthreads();
#pragma unroll
  for (int r = 0; r < 16; ++r)
    AB[((16 * r + a) << 4) | (g2 ^ a)] = pk(va[r], vb[r]);
  __syncthreads();
#pragma unroll
  for (int g = 0; g < 16; ++g) {
    float4 t = AB[(tid << 4) | (g ^ a)];
    va[g] = (v2){t.x, t.y};
    vb[g] = (v2){t.z, t.w};
  }
  tw_apply2(va, vb, (float)SIGN * (2.0f * PI_F / 4096.0f) * (float)tid);
  fft16<SIGN>(va);
  fft16<SIGN>(vb);
}

// ---------------- Kernel 1a: Cauchy sums -> atRoots (T-hoisted) ---------
// den = Q - T*L = T*(qt - L), qt = Q/T computed once. Primed sums
// S' = sum v/(qt-L); true S = S'/T. Epilogue simplifies to
// atR = (1/T) * [S01' - S23'*S45' / (1 + S67')].
__global__ __launch_bounds__(256) void k_cauchy(
    const float* __restrict__ Lre, const float* __restrict__ Lim,
    const float* __restrict__ Pri, const float* __restrict__ Bri,
    const float* __restrict__ Cri, const float* __restrict__ lstep,
    float2* __restrict__ atR) {
  __shared__ float4 pA[64];
  __shared__ float4 pB[64];
  __shared__ float2 pL[64];
  const int h = blockIdx.x >> 4;
  const int sub = blockIdx.x & 15;
  const int tid = threadIdx.x;
  if (tid < 64) {
    int base = h * 64 + tid;
    float lr = fminf(Lre[base], -1e-4f);
    float li = Lim[base];
    float pr = Pri[2 * base], pi = Pri[2 * base + 1];
    float br = Bri[2 * base], bi = Bri[2 * base + 1];
    float cr = Cri[2 * base], ci = Cri[2 * base + 1];
    pA[tid] = make_float4(cr * br + ci * bi, cr * bi - ci * br,
                          cr * pr + ci * pi, cr * pi - ci * pr);
    pB[tid] = make_float4(pr * br + pi * bi, pr * bi - pi * br,
                          pr * pr + pi * pi, 0.f);
    pL[tid] = make_float2(lr, li);
  }
  __syncthreads();
  const float istep = expf(-lstep[h]);
  const int m = sub * 256 + tid;
  float sn, cn;
  __sincosf(-(2.0f * PI_F / 4096.0f) * (float)m, &sn, &cn);
  const v2 T = (v2){0.5f * (1.0f + cn), 0.5f * sn};     // (trm, tim)
  const v2 Q = (v2){(1.0f - cn) * istep, -sn * istep};  // (qrm, qim)
  // qt = Q / T, guarded at the T->0 bin (m=2048): rcp(max(|T|^2,1e-30))
  // keeps all paths finite (worst case one bin approximated; the ifft
  // spreads it as ~2e-4 per K sample, far below tolerance).
  const float t2 = T.x * T.x + T.y * T.y;
  const float rt2 = __builtin_amdgcn_rcpf(fmaxf(t2, 1e-30f));
  const v2 qt = cmulcj(Q, T) * (v2){rt2, rt2};
  v2 S01 = (v2){0.f, 0.f}, S23 = (v2){0.f, 0.f}, S45 = (v2){0.f, 0.f},
     S67 = (v2){0.f, 0.f};
#pragma unroll 8
  for (int n = 0; n < 64; ++n) {
    float4 a = pA[n];
    float4 b = pB[n];
    v2 L = tov2(pL[n]);
    v2 d = qt - L;  // was Q - cmul(T,L): 3 packed ops -> 1
    float inv = __builtin_amdgcn_rcpf(d.x * d.x + d.y * d.y);
    v2 s = d * (v2){inv, -inv};  // (sr, si) ~ 1/(qt-L)
    S01 += cmul((v2){a.x, a.y}, s);
    S23 += cmul((v2){a.z, a.w}, s);
    S45 += cmul((v2){b.x, b.y}, s);
    S67 += (v2){b.z, b.z} * s;
  }
  // epilogue: atR = (1/T) [S01' - S23'S45'/(1+S67')]
  v2 den = (v2){1.0f + S67.x, S67.y};
  float dinv = 1.0f / (den.x * den.x + den.y * den.y);
  v2 num = cmul(S23, S45);
  v2 quot = cmulcj(num, den) * (v2){dinv, dinv};
  v2 res = S01 - quot;
  v2 out = cmulcj(res, T) * (v2){rt2, rt2};  // * conj(T)/|T|^2 = /T
  atR[h * 4096 + m] = tof2(out);
}

// ------- Kernel 1b: atRoots -> alpha/beta table (radix-16 scramble) -----
__global__ __launch_bounds__(256, 4) void k_khat(
    const float2* __restrict__ atR, const float* __restrict__ Dp,
    float4* __restrict__ abt) {
  __shared__ float2 lds[4368];
  const int h = blockIdx.x;
  const int tid = threadIdx.x;
  v2 v[16];
#pragma unroll
  for (int c = 0; c < 16; ++c) v[c] = tov2(atR[h * 4096 + tid + 256 * c]);
  fft4096_regs<1, false>(v, lds, tid);  // unnorm inverse -> zK (scrambled)
  const int kb = (tid >> 4) + 16 * (tid & 15);
  float* ldsf = (float*)lds;
  const float s = 1.0f / 4096.0f;
  __syncthreads();
#pragma unroll
  for (int al = 0; al < 16; ++al) ldsf[ad(kb + 256 * al)] = v[al].x * s;
  __syncthreads();
#pragma unroll
  for (int c = 0; c < 8; ++c) {
    int n = tid + 256 * c;
    v[c] = (v2){ldsf[ad(2 * n)], ldsf[ad(2 * n + 1)]};
  }
#pragma unroll
  for (int c = 8; c < 16; ++c) v[c] = (v2){0.f, 0.f};
  fft4096_regs<-1, true>(v, lds, tid);  // forward; scrambled; zero half
  __syncthreads();
#pragma unroll
  for (int al = 0; al < 16; ++al) lds[ad(kb + 256 * al)] = tof2(v[al]);
  __syncthreads();
  const float Dh = Dp[h];
#pragma unroll
  for (int c = 0; c < 16; ++c) {
    int k = kb + 256 * c;
    float2 Zk = lds[ad(k)];
    float2 Zm = lds[ad((4096 - k) & 4095)];
    float Er = 0.5f * (Zk.x + Zm.x), Ei = 0.5f * (Zk.y - Zm.y);
    float Or = 0.5f * (Zk.y + Zm.y), Oi = 0.5f * (Zm.x - Zk.x);
    float s_, c_;
    __sincosf(-(PI_F / 4096.0f) * (float)k, &s_, &c_);
    float Gr = c_ * Or - s_ * Oi, Gi = c_ * Oi + s_ * Or;  // G = W*O
    float ar = (Er + Dh + s_ * Gr) * s;
    float ai = (Ei + s_ * Gi) * s;
    float br = (-c_ * Gi) * s;
    float bi = (c_ * Gr) * s;
    abt[h * 4096 + tid + 256 * c] = make_float4(ar, ai, br, bi);  // scrambled
  }
}

// ---------------- Kernel 2: dual-row FFT convolution (R4 state) --------
// 1024 blocks: block i does rows i and i+1024 (same h, batches b and b+8).
__global__ __launch_bounds__(256, 1) void k_conv2(
    const float* __restrict__ u, const float4* __restrict__ abt,
    float* __restrict__ y) {
  __shared__ float4 AB[4096];  // 64 KB: interleaved {rowA,rowB} per bin
  const int i = blockIdx.x;  // 0..1023
  const int h = i & 127;
  const int tid = threadIdx.x;
  const float2* uA = (const float2*)(u + (size_t)i * 4096);
  const float2* uB = (const float2*)(u + (size_t)(i + 1024) * 4096);
  v2 va[16], vb[16];
#pragma unroll
  for (int c = 0; c < 8; ++c) {
    va[c] = tov2(uA[tid + 256 * c]);
    vb[c] = tov2(uB[tid + 256 * c]);
  }
#pragma unroll
  for (int c = 8; c < 16; ++c) {
    va[c] = (v2){0.f, 0.f};
    vb[c] = (v2){0.f, 0.f};
  }
  fft4096_x2<-1>(va, vb, AB, tid);  // forward; v[al]=Z[kb+256al]
  const int kb = (tid >> 4) + 16 * (tid & 15);
  __syncthreads();  // lagging T2 reads done before overwrite
#pragma unroll
  for (int al = 0; al < 16; ++al)
    AB[sw16(kb + 256 * al)] = pk(va[al], vb[al]);
  __syncthreads();
  const float4* __restrict__ abrow = abt + h * 4096;
#pragma unroll
  for (int al = 0; al < 16; ++al) {
    int k = kb + 256 * al;
    float4 zm = AB[sw16((4096 - k) & 4095)];  // {Zma, Zmb} one b128
    float4 ab = abrow[tid + 256 * al];        // one load serves both rows
    v2 alpha = (v2){ab.x, ab.y};
    v2 beta = (v2){ab.z, ab.w};
    // y = alpha*Z + beta*conj(Zm)   (packed: 2 cmul + add per row)
    va[al] = cmul(alpha, va[al]) + cmulcj(beta, (v2){zm.x, zm.y});
    vb[al] = cmul(alpha, vb[al]) + cmulcj(beta, (v2){zm.z, zm.w});
  }
  fft4096_x2_s2n<1>(va, vb, AB, tid);  // inverse (scale folded in ab)
  float2* yA = (float2*)(y + (size_t)i * 4096);
  float2* yB = (float2*)(y + (size_t)(i + 1024) * 4096);
#pragma unroll
  for (int c = 0; c < 8; ++c) {
    yA[tid + 256 * c] = tof2(va[c]);
    yB[tid + 256 * c] = tof2(vb[c]);
  }
}

extern "C" void kernel_launch(void* const* d_in, const int* in_sizes, int n_in,
                              void* d_out, int out_size, void* d_ws,
                              size_t ws_size, hipStream_t stream) {
  (void)in_sizes; (void)n_in; (void)out_size; (void)ws_size;
  const float* u = (const float*)d_in[0];
  const float* Lre = (const float*)d_in[1];
  const float* Lim = (const float*)d_in[2];
  const float* Pri = (const float*)d_in[3];
  const float* Bri = (const float*)d_in[4];
  const float* Cri = (const float*)d_in[5];
  const float* lst = (const float*)d_in[6];
  const float* Dp = (const float*)d_in[7];
  float* y = (float*)d_out;
  float2* atR = (float2*)d_ws;                                     // 4 MiB
  float4* abt = (float4*)((char*)d_ws + (size_t)4 * 1024 * 1024);  // 8 MiB

  k_cauchy<<<2048, 256, 0, stream>>>(Lre, Lim, Pri, Bri, Cri, lst, atR);
  k_khat<<<128, 256, 0, stream>>>(atR, Dp, abt);
  k_conv2<<<1024, 256, 0, stream>>>(u, abt, y);
}

// Round 9
// 141.235 us; speedup vs baseline: 1.3503x; 1.0054x over previous
//
#include <hip/hip_runtime.h>
#include <hip/hip_bf16.h>

// S4 layer: y = irfft( rfft(pad(u)) * (rfft(pad(K)) + D) )[:L]
// B=16, H=128, L=4096, N=64. All fp32.
// k_conv2: DUAL-ROW radix-16 FFT4096, interleaved float4 64KB LDS (R2),
// packed v_pk math (R3), fft16z + split twiddle chains (R4). Occupancy
// thesis dead (R5/R6). conv2 frozen at R4 structure.
// R7: T-hoist -> fast but absmax 3x (cancellation in 1+cos near m=2048).
// R8: half-angle reform (qt = -2i*istep*tan(th), 1/T = 1-i*tan(th)) --
// cancellation-free BUT unguarded s2/c2: hardware cos(-pi/2) == 0 at
// m=2048 -> t=inf -> gh=inf -> |d|^2=inf -> rcp=0 -> inf*0 = NaN. FAILED.
// R9 (this round): R8 + the guard: |c2| clamped to >=1e-10 (sign kept).
// t <= ~1e10, gh <= 2e13 (istep<=1000), gh^2 ~ 4e26: all finite. At the
// clamped bin the value approaches the analytic limit step/2*sum(v)
// (t-independent to leading order) -> error O(1/t), negligible.
// Threshold learned from R8 log: 0.1575 (R7's 0.09375 had margin).
// ws: [0,4MiB) atR 128x4096 float2 ; [4MiB,12MiB) abt 128x4096 float4
//   (abt scrambled in radix-16 order: slot tid+256c <-> k=kb+256c).

#define PI_F 3.14159265358979323846f

typedef float v2 __attribute__((ext_vector_type(2)));

__device__ __forceinline__ v2 tov2(float2 a) { return (v2){a.x, a.y}; }
__device__ __forceinline__ float2 tof2(v2 a) { return make_float2(a.x, a.y); }

// packed complex mul: 2x v_pk (mul + fma), swizzles fold to op_sel/neg
__device__ __forceinline__ v2 cmul(v2 a, v2 b) {
  v2 t = __builtin_shufflevector(a, a, 0, 0) * b;          // (ax bx, ax by)
  v2 bs = __builtin_shufflevector(b, b, 1, 0);             // (by, bx)
  v2 m = (v2){-bs.x, bs.y};                                // (-by, bx)
  return __builtin_shufflevector(a, a, 1, 1) * m + t;
}
// packed complex mul by constant (wr, wi)
__device__ __forceinline__ v2 cmulc(v2 a, float wr, float wi) {
  v2 t = __builtin_shufflevector(a, a, 0, 0) * (v2){wr, wi};
  return __builtin_shufflevector(a, a, 1, 1) * (v2){-wi, wr} + t;
}
// a * conj(b), packed
__device__ __forceinline__ v2 cmulcj(v2 a, v2 b) {
  v2 bc = (v2){b.x, -b.y};
  return cmul(a, bc);
}

__device__ __forceinline__ int ad(int k) { return k + (k >> 4); }   // pad-17
__device__ __forceinline__ int sw16(int j) { return j ^ ((j >> 4) & 15); }

template <int SIGN>
__device__ __forceinline__ void bfly4(v2& a, v2& b, v2& c, v2& d) {
  v2 t0 = a + c, t1 = a - c, t2 = b + d, t3 = b - d;
  a = t0 + t2;
  c = t0 - t2;
  v2 t3i = (v2){t3.y, -t3.x};  // -i * t3 (sign handled below)
  if (SIGN < 0) {
    b = t1 + t3i;
    d = t1 - t3i;
  } else {
    b = t1 - t3i;
    d = t1 + t3i;
  }
}

// shared tail of the 16-point DFT: constant twiddle layer + 2nd bfly layer
template <int SIGN>
__device__ __forceinline__ void fft16_tail(v2 v[16]) {
  const float sg = (float)SIGN;
  const float C1 = 0.92387953251128674f;
  const float S1 = 0.38268343236508978f;
  const float R2 = 0.70710678118654752f;
  v[5] = cmulc(v[5], C1, sg * S1);
  v[6] = cmulc(v[6], R2, sg * R2);
  v[7] = cmulc(v[7], S1, sg * C1);
  v[9] = cmulc(v[9], R2, sg * R2);
  v[10] = (SIGN < 0) ? (v2){v[10].y, -v[10].x} : (v2){-v[10].y, v[10].x};
  v[11] = cmulc(v[11], -R2, sg * R2);
  v[13] = cmulc(v[13], S1, sg * C1);
  v[14] = cmulc(v[14], -R2, sg * R2);
  v[15] = cmulc(v[15], -C1, -sg * S1);
  v2 w[16];
#pragma unroll
  for (int g = 0; g < 4; ++g) {
    v2 x0 = v[4 * g], x1 = v[4 * g + 1], x2 = v[4 * g + 2], x3 = v[4 * g + 3];
    bfly4<SIGN>(x0, x1, x2, x3);
    w[g] = x0; w[g + 4] = x1; w[g + 8] = x2; w[g + 12] = x3;
  }
#pragma unroll
  for (int i = 0; i < 16; ++i) v[i] = w[i];
}

// full 16-point DFT, natural in / natural out
template <int SIGN>
__device__ __forceinline__ void fft16(v2 v[16]) {
  bfly4<SIGN>(v[0], v[4], v[8], v[12]);
  bfly4<SIGN>(v[1], v[5], v[9], v[13]);
  bfly4<SIGN>(v[2], v[6], v[10], v[14]);
  bfly4<SIGN>(v[3], v[7], v[11], v[15]);
  fft16_tail<SIGN>(v);
}

// 16-point DFT with v[8..15] == 0 on entry (zero-padded half): stage-1
// bfly4 with c=d=0 collapses to 4 packed ops (a+b, a-b, a+-ib).
template <int SIGN>
__device__ __forceinline__ void fft16z(v2 v[16]) {
#pragma unroll
  for (int g = 0; g < 4; ++g) {
    v2 A = v[g], Bv = v[4 + g];
    v2 iB = (v2){Bv.y, -Bv.x};  // -i*B
    v[g] = A + Bv;
    v[8 + g] = A - Bv;
    if (SIGN < 0) {
      v[4 + g] = A + iB;
      v[12 + g] = A - iB;
    } else {
      v[4 + g] = A - iB;
      v[12 + g] = A + iB;
    }
  }
  fft16_tail<SIGN>(v);
}

// twiddles via two parallel running chains: cw walks w^1..w^7, cw2 walks
// w^8..w^15 from a sincos(8*ang) anchor. Depth 14 -> 7, +1 live v2 only.
__device__ __forceinline__ void tw_apply(v2 v[16], float ang) {
  float sn, cn, sn8, cn8;
  __sincosf(ang, &sn, &cn);
  __sincosf(8.0f * ang, &sn8, &cn8);
  v2 w1 = (v2){cn, sn}, cw = w1;
  v2 cw2 = (v2){cn8, sn8};
  v[8] = cmul(v[8], cw2);
#pragma unroll
  for (int g = 1; g < 8; ++g) {
    v[g] = cmul(v[g], cw);
    cw2 = cmul(cw2, w1);
    v[g + 8] = cmul(v[g + 8], cw2);
    if (g < 7) cw = cmul(cw, w1);
  }
}

__device__ __forceinline__ void tw_apply2(v2 va[16], v2 vb[16], float ang) {
  float sn, cn, sn8, cn8;
  __sincosf(ang, &sn, &cn);
  __sincosf(8.0f * ang, &sn8, &cn8);
  v2 w1 = (v2){cn, sn}, cw = w1;
  v2 cw2 = (v2){cn8, sn8};
  va[8] = cmul(va[8], cw2);
  vb[8] = cmul(vb[8], cw2);
#pragma unroll
  for (int g = 1; g < 8; ++g) {
    va[g] = cmul(va[g], cw);
    vb[g] = cmul(vb[g], cw);
    cw2 = cmul(cw2, w1);
    va[g + 8] = cmul(va[g + 8], cw2);
    vb[g + 8] = cmul(vb[g + 8], cw2);
    if (g < 7) cw = cmul(cw, w1);
  }
}

// ======== pad-17 single-row machinery (k_khat only; proven) ========
// ZHI: input has v[8..15] == 0 (second khat FFT) -> cheap first stage.
template <int SIGN, bool ZHI>
__device__ void fft4096_regs(v2 v[16], float2* lds, int tid) {
  const int a = tid & 15, g2 = tid >> 4;
  if (ZHI) fft16z<SIGN>(v); else fft16<SIGN>(v);
  tw_apply(v, (float)SIGN * (2.0f * PI_F / 4096.0f) * (float)tid);
  __syncthreads();
#pragma unroll
  for (int g = 0; g < 16; ++g) lds[tid * 17 + g] = tof2(v[g]);
  __syncthreads();
#pragma unroll
  for (int b = 0; b < 16; ++b) v[b] = tov2(lds[a * 17 + b * 272 + g2]);
  fft16<SIGN>(v);
  tw_apply(v, (float)SIGN * (2.0f * PI_F / 256.0f) * (float)a);
  __syncthreads();
#pragma unroll
  for (int b = 0; b < 16; ++b) lds[g2 * 17 + b * 273 + a] = tof2(v[b]);
  __syncthreads();
#pragma unroll
  for (int a2 = 0; a2 < 16; ++a2) v[a2] = tov2(lds[g2 * 17 + a * 273 + a2]);
  fft16<SIGN>(v);
  // no trailing barrier; callers must __syncthreads before reusing lds.
}

// pack/unpack helpers for interleaved dual-row LDS (one b128 per pair)
__device__ __forceinline__ float4 pk(v2 a, v2 b) {
  return make_float4(a.x, a.y, b.x, b.y);
}

// ======== dual-row swizzled forward: natural -> scrambled ========
// Entry: va[8..15] = vb[8..15] = 0 (zero-padded conv input) -> fft16z.
// AB[s] holds {rowA, rowB} interleaved: one ds_write_b128/ds_read_b128
// moves both rows (half the DS ops of split A/B buffers).
template <int SIGN>
__device__ void fft4096_x2(v2 va[16], v2 vb[16], float4* AB, int tid) {
  const int a = tid & 15, g2 = tid >> 4;
  fft16z<SIGN>(va);
  fft16z<SIGN>(vb);
  tw_apply2(va, vb, (float)SIGN * (2.0f * PI_F / 4096.0f) * (float)tid);
  __syncthreads();
#pragma unroll
  for (int g = 0; g < 16; ++g) AB[(tid << 4) | (g ^ a)] = pk(va[g], vb[g]);
  __syncthreads();
#pragma unroll
  for (int b = 0; b < 16; ++b) {
    float4 t = AB[((a + 16 * b) << 4) | (g2 ^ a)];
    va[b] = (v2){t.x, t.y};
    vb[b] = (v2){t.z, t.w};
  }
  fft16<SIGN>(va);
  fft16<SIGN>(vb);
  tw_apply2(va, vb, (float)SIGN * (2.0f * PI_F / 256.0f) * (float)a);
  __syncthreads();
#pragma unroll
  for (int b = 0; b < 16; ++b)
    AB[(g2 << 8) | (b << 4) | (a ^ b)] = pk(va[b], vb[b]);
  __syncthreads();
#pragma unroll
  for (int a2 = 0; a2 < 16; ++a2) {
    float4 t = AB[(g2 << 8) | (a << 4) | (a2 ^ a)];
    va[a2] = (v2){t.x, t.y};
    vb[a2] = (v2){t.z, t.w};
  }
  fft16<SIGN>(va);
  fft16<SIGN>(vb);
  // no trailing barrier.
}

// ======== dual-row swizzled inverse: scrambled -> natural ========
template <int SIGN>
__device__ void fft4096_x2_s2n(v2 va[16], v2 vb[16], float4* AB, int tid) {
  const int a = tid & 15, g2 = tid >> 4;
  fft16<SIGN>(va);
  fft16<SIGN>(vb);
  __syncthreads();  // guard callers' prior lds reads
#pragma unroll
  for (int r = 0; r < 16; ++r)
    AB[(g2 << 8) | (a << 4) | (r ^ a)] = pk(va[r], vb[r]);
  __syncthreads();
#pragma unroll
  for (int b = 0; b < 16; ++b) {
    float4 t = AB[(g2 << 8) | (b << 4) | (a ^ b)];
    va[b] = (v2){t.x, t.y};
    vb[b] = (v2){t.z, t.w};
  }
  tw_apply2(va, vb, (float)SIGN * (2.0f * PI_F / 256.0f) * (float)a);
  fft16<SIGN>(va);
  fft16<SIGN>(vb);
  __syncthreads();
#pragma unroll
  for (int r = 0; r < 16; ++r)
    AB[((16 * r + a) << 4) | (g2 ^ a)] = pk(va[r], vb[r]);
  __syncthreads();
#pragma unroll
  for (int g = 0; g < 16; ++g) {
    float4 t = AB[(tid << 4) | (g ^ a)];
    va[g] = (v2){t.x, t.y};
    vb[g] = (v2){t.z, t.w};
  }
  tw_apply2(va, vb, (float)SIGN * (2.0f * PI_F / 4096.0f) * (float)tid);
  fft16<SIGN>(va);
  fft16<SIGN>(vb);
}

// ---------------- Kernel 1a: Cauchy sums -> atRoots -----------------
// Half-angle T-hoist (cancellation-free) + singular-bin guard:
//   th = -pi*m/4096, t = tan(th) = s2/c2g, c2g = sign(c2)*max(|c2|,1e-10)
//   qt = (0, -2*istep*t)  ;  1/T = 1 - i*t
// Loop: s ~ 1/(qt - L). Epilogue: atR = (S01'-S23'S45'/(1+S67'))*(1-i*t).
__global__ __launch_bounds__(256) void k_cauchy(
    const float* __restrict__ Lre, const float* __restrict__ Lim,
    const float* __restrict__ Pri, const float* __restrict__ Bri,
    const float* __restrict__ Cri, const float* __restrict__ lstep,
    float2* __restrict__ atR) {
  __shared__ float4 pA[64];
  __shared__ float4 pB[64];
  __shared__ float2 pL[64];
  const int h = blockIdx.x >> 4;
  const int sub = blockIdx.x & 15;
  const int tid = threadIdx.x;
  if (tid < 64) {
    int base = h * 64 + tid;
    float lr = fminf(Lre[base], -1e-4f);
    float li = Lim[base];
    float pr = Pri[2 * base], pi = Pri[2 * base + 1];
    float br = Bri[2 * base], bi = Bri[2 * base + 1];
    float cr = Cri[2 * base], ci = Cri[2 * base + 1];
    pA[tid] = make_float4(cr * br + ci * bi, cr * bi - ci * br,
                          cr * pr + ci * pi, cr * pi - ci * pr);
    pB[tid] = make_float4(pr * br + pi * bi, pr * bi - pi * br,
                          pr * pr + pi * pi, 0.f);
    pL[tid] = make_float2(lr, li);
  }
  __syncthreads();
  const float istep = expf(-lstep[h]);
  const int m = sub * 256 + tid;
  // half-angle th = theta/2 = -pi*m/4096; no 1+cos anywhere.
  float s2, c2;
  __sincosf(-(PI_F / 4096.0f) * (float)m, &s2, &c2);
  // GUARD (R8 NaN fix): hardware cos == 0 exactly at m=2048; clamp |c2|
  // so t stays finite (<=1e10). gh <= 2e13 (istep<=1000), gh^2 ~ 4e26.
  const float c2g = copysignf(fmaxf(fabsf(c2), 1e-10f), c2);
  const float t = s2 / c2g;            // tan(th), finite everywhere
  const float gh = -2.0f * istep * t;  // qt = (0, gh), purely imaginary
  const v2 G = (v2){0.f, gh};
  v2 S01 = (v2){0.f, 0.f}, S23 = (v2){0.f, 0.f}, S45 = (v2){0.f, 0.f},
     S67 = (v2){0.f, 0.f};
#pragma unroll 8
  for (int n = 0; n < 64; ++n) {
    float4 a = pA[n];
    float4 b = pB[n];
    v2 L = tov2(pL[n]);
    v2 d = G - L;  // 1 packed op
    float inv = __builtin_amdgcn_rcpf(d.x * d.x + d.y * d.y);
    v2 s = d * (v2){inv, -inv};  // (sr, si) ~ 1/(qt - L)
    S01 += cmul((v2){a.x, a.y}, s);
    S23 += cmul((v2){a.z, a.w}, s);
    S45 += cmul((v2){b.x, b.y}, s);
    S67 += (v2){b.z, b.z} * s;
  }
  // epilogue: res = S01' - S23'S45'/(1+S67'); atR = res * (1 - i*t)
  v2 den = (v2){1.0f + S67.x, S67.y};
  float dinv = 1.0f / (den.x * den.x + den.y * den.y);
  v2 num = cmul(S23, S45);
  v2 quot = cmulcj(num, den) * (v2){dinv, dinv};
  v2 res = S01 - quot;
  v2 out = (v2){res.x + t * res.y, res.y - t * res.x};  // res * (1 - i t)
  atR[h * 4096 + m] = tof2(out);
}

// ------- Kernel 1b: atRoots -> alpha/beta table (radix-16 scramble) -----
__global__ __launch_bounds__(256, 4) void k_khat(
    const float2* __restrict__ atR, const float* __restrict__ Dp,
    float4* __restrict__ abt) {
  __shared__ float2 lds[4368];
  const int h = blockIdx.x;
  const int tid = threadIdx.x;
  v2 v[16];
#pragma unroll
  for (int c = 0; c < 16; ++c) v[c] = tov2(atR[h * 4096 + tid + 256 * c]);
  fft4096_regs<1, false>(v, lds, tid);  // unnorm inverse -> zK (scrambled)
  const int kb = (tid >> 4) + 16 * (tid & 15);
  float* ldsf = (float*)lds;
  const float s = 1.0f / 4096.0f;
  __syncthreads();
#pragma unroll
  for (int al = 0; al < 16; ++al) ldsf[ad(kb + 256 * al)] = v[al].x * s;
  __syncthreads();
#pragma unroll
  for (int c = 0; c < 8; ++c) {
    int n = tid + 256 * c;
    v[c] = (v2){ldsf[ad(2 * n)], ldsf[ad(2 * n + 1)]};
  }
#pragma unroll
  for (int c = 8; c < 16; ++c) v[c] = (v2){0.f, 0.f};
  fft4096_regs<-1, true>(v, lds, tid);  // forward; scrambled; zero half
  __syncthreads();
#pragma unroll
  for (int al = 0; al < 16; ++al) lds[ad(kb + 256 * al)] = tof2(v[al]);
  __syncthreads();
  const float Dh = Dp[h];
#pragma unroll
  for (int c = 0; c < 16; ++c) {
    int k = kb + 256 * c;
    float2 Zk = lds[ad(k)];
    float2 Zm = lds[ad((4096 - k) & 4095)];
    float Er = 0.5f * (Zk.x + Zm.x), Ei = 0.5f * (Zk.y - Zm.y);
    float Or = 0.5f * (Zk.y + Zm.y), Oi = 0.5f * (Zm.x - Zk.x);
    float s_, c_;
    __sincosf(-(PI_F / 4096.0f) * (float)k, &s_, &c_);
    float Gr = c_ * Or - s_ * Oi, Gi = c_ * Oi + s_ * Or;  // G = W*O
    float ar = (Er + Dh + s_ * Gr) * s;
    float ai = (Ei + s_ * Gi) * s;
    float br = (-c_ * Gi) * s;
    float bi = (c_ * Gr) * s;
    abt[h * 4096 + tid + 256 * c] = make_float4(ar, ai, br, bi);  // scrambled
  }
}

// ---------------- Kernel 2: dual-row FFT convolution (R4 state) --------
// 1024 blocks: block i does rows i and i+1024 (same h, batches b and b+8).
__global__ __launch_bounds__(256, 1) void k_conv2(
    const float* __restrict__ u, const float4* __restrict__ abt,
    float* __restrict__ y) {
  __shared__ float4 AB[4096];  // 64 KB: interleaved {rowA,rowB} per bin
  const int i = blockIdx.x;  // 0..1023
  const int h = i & 127;
  const int tid = threadIdx.x;
  const float2* uA = (const float2*)(u + (size_t)i * 4096);
  const float2* uB = (const float2*)(u + (size_t)(i + 1024) * 4096);
  v2 va[16], vb[16];
#pragma unroll
  for (int c = 0; c < 8; ++c) {
    va[c] = tov2(uA[tid + 256 * c]);
    vb[c] = tov2(uB[tid + 256 * c]);
  }
#pragma unroll
  for (int c = 8; c < 16; ++c) {
    va[c] = (v2){0.f, 0.f};
    vb[c] = (v2){0.f, 0.f};
  }
  fft4096_x2<-1>(va, vb, AB, tid);  // forward; v[al]=Z[kb+256al]
  const int kb = (tid >> 4) + 16 * (tid & 15);
  __syncthreads();  // lagging T2 reads done before overwrite
#pragma unroll
  for (int al = 0; al < 16; ++al)
    AB[sw16(kb + 256 * al)] = pk(va[al], vb[al]);
  __syncthreads();
  const float4* __restrict__ abrow = abt + h * 4096;
#pragma unroll
  for (int al = 0; al < 16; ++al) {
    int k = kb + 256 * al;
    float4 zm = AB[sw16((4096 - k) & 4095)];  // {Zma, Zmb} one b128
    float4 ab = abrow[tid + 256 * al];        // one load serves both rows
    v2 alpha = (v2){ab.x, ab.y};
    v2 beta = (v2){ab.z, ab.w};
    // y = alpha*Z + beta*conj(Zm)   (packed: 2 cmul + add per row)
    va[al] = cmul(alpha, va[al]) + cmulcj(beta, (v2){zm.x, zm.y});
    vb[al] = cmul(alpha, vb[al]) + cmulcj(beta, (v2){zm.z, zm.w});
  }
  fft4096_x2_s2n<1>(va, vb, AB, tid);  // inverse (scale folded in ab)
  float2* yA = (float2*)(y + (size_t)i * 4096);
  float2* yB = (float2*)(y + (size_t)(i + 1024) * 4096);
#pragma unroll
  for (int c = 0; c < 8; ++c) {
    yA[tid + 256 * c] = tof2(va[c]);
    yB[tid + 256 * c] = tof2(vb[c]);
  }
}

extern "C" void kernel_launch(void* const* d_in, const int* in_sizes, int n_in,
                              void* d_out, int out_size, void* d_ws,
                              size_t ws_size, hipStream_t stream) {
  (void)in_sizes; (void)n_in; (void)out_size; (void)ws_size;
  const float* u = (const float*)d_in[0];
  const float* Lre = (const float*)d_in[1];
  const float* Lim = (const float*)d_in[2];
  const float* Pri = (const float*)d_in[3];
  const float* Bri = (const float*)d_in[4];
  const float* Cri = (const float*)d_in[5];
  const float* lst = (const float*)d_in[6];
  const float* Dp = (const float*)d_in[7];
  float* y = (float*)d_out;
  float2* atR = (float2*)d_ws;                                     // 4 MiB
  float4* abt = (float4*)((char*)d_ws + (size_t)4 * 1024 * 1024);  // 8 MiB

  k_cauchy<<<2048, 256, 0, stream>>>(Lre, Lim, Pri, Bri, Cri, lst, atR);
  k_khat<<<128, 256, 0, stream>>>(atR, Dp, abt);
  k_conv2<<<1024, 256, 0, stream>>>(u, abt, y);
}